// Round 3
// baseline (1867.808 us; speedup 1.0000x reference)
//
#include <hip/hip_runtime.h>
#include <hip/hip_bf16.h>

typedef __bf16 bf16_t;
typedef __attribute__((ext_vector_type(8))) __bf16 bf16x8;
typedef __attribute__((ext_vector_type(4))) float floatx4;

#define MFMA16x16x32(a, b, c) __builtin_amdgcn_mfma_f32_16x16x32_bf16((a), (b), (c), 0, 0, 0)

// ---------------------------------------------------------------------------
// On-device dtype sniffer. For bf16-pair-packed u32, bits 14..7 are the low
// element's exponent: N(0,1)-ish bf16 -> in [112,142] nearly always. For fp32,
// those bits are uniform mantissa bits -> ~12% hit rate. Deterministic,
// block-uniform, same result every call (reads pristine input hs).
// ---------------------------------------------------------------------------
__device__ __forceinline__ bool detect_bf16(const void* hs) {
    const unsigned* u = (const unsigned*)hs;
    int c = 0;
#pragma unroll 8
    for (int i = 0; i < 64; i++) {
        unsigned e = (u[i] >> 7) & 0xFFu;
        c += (e >= 112u && e <= 142u) ? 1 : 0;
    }
    return c >= 32;
}

// ---------------------------------------------------------------------------
// 64x64-tiled transpose of a 4096x2048 weight stripe into bf16 Wt[2048][4096]:
// Wt[c][r] = (bf16)W[r][coff + c]. Source dtype sniffed from hs.
// ---------------------------------------------------------------------------
__global__ __launch_bounds__(256) void transpose_w(
    const void* __restrict__ src, bf16_t* __restrict__ dst,
    int coff, const void* __restrict__ hs) {
    const bool isbf = detect_bf16(hs);
    __shared__ bf16_t T[64 * 68];
    const int r0 = blockIdx.x * 64, c0 = blockIdx.y * 64;
    const int t = threadIdx.x;
#pragma unroll
    for (int i = 0; i < 2; i++) {
        int idx = i * 256 + t;
        int r = idx >> 3, c8 = (idx & 7) << 3;
        bf16_t tmp[8];
        if (isbf) {
            *(uint4*)tmp = *(const uint4*)((const bf16_t*)src +
                              (size_t)(r0 + r) * 4096 + coff + c0 + c8);
        } else {
            const float* s = (const float*)src + (size_t)(r0 + r) * 4096 + coff + c0 + c8;
            float4 f0 = *(const float4*)s;
            float4 f1 = *(const float4*)(s + 4);
            tmp[0] = (bf16_t)f0.x; tmp[1] = (bf16_t)f0.y;
            tmp[2] = (bf16_t)f0.z; tmp[3] = (bf16_t)f0.w;
            tmp[4] = (bf16_t)f1.x; tmp[5] = (bf16_t)f1.y;
            tmp[6] = (bf16_t)f1.z; tmp[7] = (bf16_t)f1.w;
        }
        *(uint2*)&T[r * 68 + c8]     = *(const uint2*)&tmp[0];
        *(uint2*)&T[r * 68 + c8 + 4] = *(const uint2*)&tmp[4];
    }
    __syncthreads();
#pragma unroll
    for (int i = 0; i < 2; i++) {
        int idx = i * 256 + t;
        int c = idx >> 3, r8 = (idx & 7) << 3;
        bf16_t tmp[8];
#pragma unroll
        for (int j = 0; j < 8; j++) tmp[j] = T[(r8 + j) * 68 + c];
        *(uint4*)(dst + (size_t)(c0 + c) * 4096 + r0 + r8) = *(const uint4*)tmp;
    }
}

// ---------------------------------------------------------------------------
// C[2048, n_off..+2047] = A[2048,4096] @ Wt[2048,4096]^T (stripe GEMM).
// 128x128 tile, BK=32, 4 waves, register LDS staging.
// AHS: A is hidden_states (dtype sniffed). TV: write V^T per head.
// CMAY32: C store dtype sniffed (final GEMM into d_out).
// ---------------------------------------------------------------------------
template <bool AHS, bool TV, bool CMAY32>
__global__ __launch_bounds__(256) void gemm_nt(
    const void* __restrict__ Ain, const bf16_t* __restrict__ Bt,
    void* __restrict__ Cout, int n_off, const void* __restrict__ hs) {
    constexpr int K = 4096;
    const bool isbf = (AHS || CMAY32) ? detect_bf16(hs) : true;
    __shared__ bf16_t As[128 * 32];
    __shared__ bf16_t Bs[128 * 32];
    const int t = threadIdx.x;
    const int w = t >> 6, l = t & 63, l15 = l & 15, q = l >> 4;
    const int m0 = blockIdx.y * 128, n0 = blockIdx.x * 128;
    const int wm = (w >> 1) * 64, wn = (w & 1) * 64;
    floatx4 acc[4][4];
#pragma unroll
    for (int mi = 0; mi < 4; mi++)
#pragma unroll
        for (int ni = 0; ni < 4; ni++) acc[mi][ni] = floatx4{0.f, 0.f, 0.f, 0.f};

    const int ar = t >> 2, ac = (t & 3) << 3;
    const bf16_t* Ab = (const bf16_t*)Ain;
    const float*  Af = (const float*)Ain;

    for (int k0 = 0; k0 < K; k0 += 32) {
        bf16_t a0[8], a1[8], b0[8], b1[8];
        if (AHS && !isbf) {
#pragma unroll
            for (int half = 0; half < 2; half++) {
                const float* s = Af + (size_t)(m0 + ar + half * 64) * K + k0 + ac;
                float4 f0 = *(const float4*)s;
                float4 f1 = *(const float4*)(s + 4);
                bf16_t* dstp = half ? a1 : a0;
                dstp[0] = (bf16_t)f0.x; dstp[1] = (bf16_t)f0.y;
                dstp[2] = (bf16_t)f0.z; dstp[3] = (bf16_t)f0.w;
                dstp[4] = (bf16_t)f1.x; dstp[5] = (bf16_t)f1.y;
                dstp[6] = (bf16_t)f1.z; dstp[7] = (bf16_t)f1.w;
            }
        } else {
            *(uint4*)a0 = *(const uint4*)(Ab + (size_t)(m0 + ar) * K + k0 + ac);
            *(uint4*)a1 = *(const uint4*)(Ab + (size_t)(m0 + ar + 64) * K + k0 + ac);
        }
        *(uint4*)b0 = *(const uint4*)(Bt + (size_t)(n0 + ar) * K + k0 + ac);
        *(uint4*)b1 = *(const uint4*)(Bt + (size_t)(n0 + ar + 64) * K + k0 + ac);

        __syncthreads();
        *(uint4*)&As[ar * 32 + ac]        = *(const uint4*)a0;
        *(uint4*)&As[(ar + 64) * 32 + ac] = *(const uint4*)a1;
        *(uint4*)&Bs[ar * 32 + ac]        = *(const uint4*)b0;
        *(uint4*)&Bs[(ar + 64) * 32 + ac] = *(const uint4*)b1;
        __syncthreads();

        bf16x8 af[4], bfr[4];
#pragma unroll
        for (int i = 0; i < 4; i++)
            af[i] = *(const bf16x8*)&As[(wm + i * 16 + l15) * 32 + q * 8];
#pragma unroll
        for (int i = 0; i < 4; i++)
            bfr[i] = *(const bf16x8*)&Bs[(wn + i * 16 + l15) * 32 + q * 8];
#pragma unroll
        for (int mi = 0; mi < 4; mi++)
#pragma unroll
            for (int ni = 0; ni < 4; ni++)
                acc[mi][ni] = MFMA16x16x32(af[mi], bfr[ni], acc[mi][ni]);
    }

    if (TV) {
        bf16_t* C = (bf16_t*)Cout;
#pragma unroll
        for (int mi = 0; mi < 4; mi++) {
            int s_base = m0 + wm + mi * 16 + q * 4;
#pragma unroll
            for (int ni = 0; ni < 4; ni++) {
                int e = n_off + n0 + wn + ni * 16 + l15;
                int h = e >> 8, dd = e & 255;
                bf16_t o4[4];
#pragma unroll
                for (int r = 0; r < 4; r++) o4[r] = (bf16_t)acc[mi][ni][r];
                *(uint2*)(C + (size_t)h * 524288 + (size_t)dd * 2048 + s_base) =
                    *(const uint2*)o4;
            }
        }
    } else if (CMAY32 && !isbf) {
        float* C = (float*)Cout;
#pragma unroll
        for (int mi = 0; mi < 4; mi++)
#pragma unroll
            for (int ni = 0; ni < 4; ni++)
#pragma unroll
                for (int r = 0; r < 4; r++) {
                    int row = m0 + wm + mi * 16 + q * 4 + r;
                    int col = n_off + n0 + wn + ni * 16 + l15;
                    C[(size_t)row * 4096 + col] = acc[mi][ni][r];
                }
    } else {
        bf16_t* C = (bf16_t*)Cout;
#pragma unroll
        for (int mi = 0; mi < 4; mi++)
#pragma unroll
            for (int ni = 0; ni < 4; ni++)
#pragma unroll
                for (int r = 0; r < 4; r++) {
                    int row = m0 + wm + mi * 16 + q * 4 + r;
                    int col = n_off + n0 + wn + ni * 16 + l15;
                    C[(size_t)row * 4096 + col] = (bf16_t)acc[mi][ni][r];
                }
    }
}

// ---------------------------------------------------------------------------
// GPT-J interleaved RoPE on first 64 dims of each 256-dim head, Q and K (bf16).
// ---------------------------------------------------------------------------
__global__ __launch_bounds__(256) void rope_qk(
    bf16_t* __restrict__ Q, bf16_t* __restrict__ K,
    const int* __restrict__ pos_ids) {
    int tid = blockIdx.x * 256 + threadIdx.x;
    int i = tid & 31;
    int h = (tid >> 5) & 15;
    int s = tid >> 9;
    float p = (float)pos_ids[s];
    float inv = __expf(-(float)i * 0.28782313662425572f);  // 10000^(-i/32)
    float ang = p * inv;
    float sn, cs;
    __sincosf(ang, &sn, &cs);
    size_t base = (size_t)s * 4096 + h * 256 + 2 * i;
    float q0 = (float)Q[base], q1 = (float)Q[base + 1];
    Q[base]     = (bf16_t)(q0 * cs - q1 * sn);
    Q[base + 1] = (bf16_t)(q1 * cs + q0 * sn);
    float k0 = (float)K[base], k1 = (float)K[base + 1];
    K[base]     = (bf16_t)(k0 * cs - k1 * sn);
    K[base + 1] = (bf16_t)(k1 * cs + k0 * sn);
}

// ---------------------------------------------------------------------------
// Flash attention: block = (64 q-rows, head), 4 waves x 16 q-rows, 32-key
// tiles, online softmax, P via LDS. All buffers distinct (no aliasing).
// ---------------------------------------------------------------------------
__global__ __launch_bounds__(256) void attn_kernel(
    const bf16_t* __restrict__ Q, const bf16_t* __restrict__ K,
    const bf16_t* __restrict__ Vt, bf16_t* __restrict__ Ctx) {
    __shared__ bf16_t Ks[32 * 264];
    __shared__ bf16_t Vs[256 * 40];
    __shared__ bf16_t Ps[4 * 16 * 40];
    const int qt = blockIdx.x, h = blockIdx.y;
    const int t = threadIdx.x, w = t >> 6, l = t & 63, l15 = l & 15, q = l >> 4;
    const int qr = qt * 64 + w * 16;

    bf16x8 qf[8];
    {
        const bf16_t* qp = Q + (size_t)(qr + l15) * 4096 + h * 256 + q * 8;
#pragma unroll
        for (int tt = 0; tt < 8; tt++) qf[tt] = *(const bf16x8*)(qp + tt * 32);
    }
    floatx4 O[16];
#pragma unroll
    for (int i = 0; i < 16; i++) O[i] = floatx4{0.f, 0.f, 0.f, 0.f};
    float mrow[4] = {-1e30f, -1e30f, -1e30f, -1e30f};
    float lrow[4] = {0.f, 0.f, 0.f, 0.f};

    const int nkt = 2 * qt + 2;
    for (int kt = 0; kt < nkt; kt++) {
        __syncthreads();
#pragma unroll
        for (int i = 0; i < 4; i++) {
            int idx = i * 256 + t;
            int key = idx >> 5, d16 = (idx & 31) << 3;
            uint4 v = *(const uint4*)(K + (size_t)(kt * 32 + key) * 4096 + h * 256 + d16);
            *(uint4*)&Ks[key * 264 + d16] = v;
        }
#pragma unroll
        for (int i = 0; i < 4; i++) {
            int idx = i * 256 + t;
            int d = idx >> 2, k8 = (idx & 3) << 3;
            uint4 v = *(const uint4*)(Vt + (size_t)h * 524288 + (size_t)d * 2048 + kt * 32 + k8);
            *(uint4*)&Vs[d * 40 + k8] = v;
        }
        __syncthreads();

        floatx4 sc[2];
        sc[0] = floatx4{0.f, 0.f, 0.f, 0.f};
        sc[1] = floatx4{0.f, 0.f, 0.f, 0.f};
#pragma unroll
        for (int tt = 0; tt < 8; tt++) {
            bf16x8 k0f = *(const bf16x8*)&Ks[l15 * 264 + tt * 32 + q * 8];
            bf16x8 k1f = *(const bf16x8*)&Ks[(16 + l15) * 264 + tt * 32 + q * 8];
            sc[0] = MFMA16x16x32(qf[tt], k0f, sc[0]);
            sc[1] = MFMA16x16x32(qf[tt], k1f, sc[1]);
        }

        const bool diag = (kt >= 2 * qt);
#pragma unroll
        for (int r = 0; r < 4; r++) {
            int grow = qr + q * 4 + r;
            float v0 = sc[0][r] * 0.0625f;
            float v1 = sc[1][r] * 0.0625f;
            if (diag) {
                if (kt * 32 + l15 > grow) v0 = -1e30f;
                if (kt * 32 + 16 + l15 > grow) v1 = -1e30f;
            }
            float mx = fmaxf(v0, v1);
#pragma unroll
            for (int d = 1; d < 16; d <<= 1) mx = fmaxf(mx, __shfl_xor(mx, d, 64));
            float mnew = fmaxf(mrow[r], mx);
            float p0 = __expf(v0 - mnew), p1 = __expf(v1 - mnew);
            float rsum = p0 + p1;
#pragma unroll
            for (int d = 1; d < 16; d <<= 1) rsum += __shfl_xor(rsum, d, 64);
            float alpha = __expf(mrow[r] - mnew);
            lrow[r] = lrow[r] * alpha + rsum;
            mrow[r] = mnew;
#pragma unroll
            for (int ni = 0; ni < 16; ni++) O[ni][r] *= alpha;
            Ps[w * 640 + (q * 4 + r) * 40 + l15] = (bf16_t)p0;
            Ps[w * 640 + (q * 4 + r) * 40 + 16 + l15] = (bf16_t)p1;
        }
        __syncthreads();

        bf16x8 pf = *(const bf16x8*)&Ps[w * 640 + l15 * 40 + q * 8];
#pragma unroll
        for (int ni = 0; ni < 16; ni++) {
            bf16x8 vf = *(const bf16x8*)&Vs[(ni * 16 + l15) * 40 + q * 8];
            O[ni] = MFMA16x16x32(pf, vf, O[ni]);
        }
    }
#pragma unroll
    for (int ni = 0; ni < 16; ni++)
#pragma unroll
        for (int r = 0; r < 4; r++) {
            int grow = qr + q * 4 + r;
            Ctx[(size_t)grow * 4096 + h * 256 + ni * 16 + l15] =
                (bf16_t)(O[ni][r] / lrow[r]);
        }
}

// ---------------------------------------------------------------------------
// Workspace (48 MB): R0=[0,16M) R1=[16,32M) R2=[32,48M).
//   QKV phase: Wt stripes in R0; Q -> d_out; K -> R1; Vt -> R2.
//   attn:      Ctx -> R0 (Wt dead).
//   final:     Wt(wo) -> R1 (K dead); gemm(A=R0, B=R1, C=d_out).
// ---------------------------------------------------------------------------
extern "C" void kernel_launch(void* const* d_in, const int* in_sizes, int n_in,
                              void* d_out, int out_size, void* d_ws, size_t ws_size,
                              hipStream_t stream) {
    const void* hs = d_in[0];
    const void* wq = d_in[1];
    const void* wk = d_in[2];
    const void* wv = d_in[3];
    const void* wo = d_in[4];
    const int* pos = (const int*)d_in[5];

    char* ws = (char*)d_ws;
    bf16_t* R0 = (bf16_t*)ws;
    bf16_t* R1 = (bf16_t*)(ws + ((size_t)16 << 20));
    bf16_t* R2 = (bf16_t*)(ws + ((size_t)32 << 20));
    bf16_t* Qb  = (bf16_t*)d_out;
    bf16_t* Kb  = R1;
    bf16_t* Vt  = R2;
    bf16_t* Ctx = R0;

    dim3 tb(256);
    dim3 gT(64, 32);
    dim3 gG(16, 16);

    // Q = hs @ wq  (Q scratch in d_out)
    transpose_w<<<gT, tb, 0, stream>>>(wq, R0, 0,    hs);
    gemm_nt<true, false, false><<<gG, tb, 0, stream>>>(hs, R0, Qb, 0, hs);
    transpose_w<<<gT, tb, 0, stream>>>(wq, R0, 2048, hs);
    gemm_nt<true, false, false><<<gG, tb, 0, stream>>>(hs, R0, Qb, 2048, hs);
    // K = hs @ wk
    transpose_w<<<gT, tb, 0, stream>>>(wk, R0, 0,    hs);
    gemm_nt<true, false, false><<<gG, tb, 0, stream>>>(hs, R0, Kb, 0, hs);
    transpose_w<<<gT, tb, 0, stream>>>(wk, R0, 2048, hs);
    gemm_nt<true, false, false><<<gG, tb, 0, stream>>>(hs, R0, Kb, 2048, hs);
    // Vt = (hs @ wv)^T per head
    transpose_w<<<gT, tb, 0, stream>>>(wv, R0, 0,    hs);
    gemm_nt<true, true, false><<<gG, tb, 0, stream>>>(hs, R0, Vt, 0, hs);
    transpose_w<<<gT, tb, 0, stream>>>(wv, R0, 2048, hs);
    gemm_nt<true, true, false><<<gG, tb, 0, stream>>>(hs, R0, Vt, 2048, hs);

    rope_qk<<<dim3(4096), tb, 0, stream>>>(Qb, Kb, pos);

    attn_kernel<<<dim3(32, 16), tb, 0, stream>>>(Qb, Kb, Vt, Ctx);

    // out = Ctx @ wo  (Wt now in R1; K dead)
    transpose_w<<<gT, tb, 0, stream>>>(wo, R1, 0,    hs);
    gemm_nt<false, false, true><<<gG, tb, 0, stream>>>(Ctx, R1, d_out, 0, hs);
    transpose_w<<<gT, tb, 0, stream>>>(wo, R1, 2048, hs);
    gemm_nt<false, false, true><<<gG, tb, 0, stream>>>(Ctx, R1, d_out, 2048, hs);
}

// Round 4
// 1180.179 us; speedup vs baseline: 1.5826x; 1.5826x over previous
//
#include <hip/hip_runtime.h>
#include <hip/hip_bf16.h>

typedef __bf16 bf16_t;
typedef __attribute__((ext_vector_type(8))) __bf16 bf16x8;
typedef __attribute__((ext_vector_type(4))) float floatx4;

#define MFMA16x16x32(a, b, c) __builtin_amdgcn_mfma_f32_16x16x32_bf16((a), (b), (c), 0, 0, 0)

__device__ __forceinline__ void glld16(const bf16_t* g, bf16_t* l) {
    __builtin_amdgcn_global_load_lds(
        (const __attribute__((address_space(1))) unsigned int*)g,
        (__attribute__((address_space(3))) unsigned int*)l,
        16, 0, 0);
}

// ---------------------------------------------------------------------------
// On-device dtype sniffer (proven in round 3). For bf16-pair-packed u32, bits
// 14..7 are the low element's exponent -> in [112,142] for N(0,1)-ish data.
// For fp32 those bits are uniform mantissa bits -> ~12% hit rate.
// ---------------------------------------------------------------------------
__device__ __forceinline__ bool detect_bf16(const void* hs) {
    const unsigned* u = (const unsigned*)hs;
    int c = 0;
#pragma unroll 8
    for (int i = 0; i < 64; i++) {
        unsigned e = (u[i] >> 7) & 0xFFu;
        c += (e >= 112u && e <= 142u) ? 1 : 0;
    }
    return c >= 32;
}

// ---------------------------------------------------------------------------
// 64x64-tiled transpose of W cols [coff, coff+64*gridDim.y) into bf16
// Wt[c][r] (dst row-stride 4096). Source dtype sniffed from hs.
// ---------------------------------------------------------------------------
__global__ __launch_bounds__(256) void transpose_w(
    const void* __restrict__ src, bf16_t* __restrict__ dst,
    int coff, const void* __restrict__ hs) {
    const bool isbf = detect_bf16(hs);
    __shared__ bf16_t T[64 * 68];
    const int r0 = blockIdx.x * 64, c0 = blockIdx.y * 64;
    const int t = threadIdx.x;
#pragma unroll
    for (int i = 0; i < 2; i++) {
        int idx = i * 256 + t;
        int r = idx >> 3, c8 = (idx & 7) << 3;
        bf16_t tmp[8];
        if (isbf) {
            *(uint4*)tmp = *(const uint4*)((const bf16_t*)src +
                              (size_t)(r0 + r) * 4096 + coff + c0 + c8);
        } else {
            const float* s = (const float*)src + (size_t)(r0 + r) * 4096 + coff + c0 + c8;
            float4 f0 = *(const float4*)s;
            float4 f1 = *(const float4*)(s + 4);
            tmp[0] = (bf16_t)f0.x; tmp[1] = (bf16_t)f0.y;
            tmp[2] = (bf16_t)f0.z; tmp[3] = (bf16_t)f0.w;
            tmp[4] = (bf16_t)f1.x; tmp[5] = (bf16_t)f1.y;
            tmp[6] = (bf16_t)f1.z; tmp[7] = (bf16_t)f1.w;
        }
        *(uint2*)&T[r * 68 + c8]     = *(const uint2*)&tmp[0];
        *(uint2*)&T[r * 68 + c8 + 4] = *(const uint2*)&tmp[4];
    }
    __syncthreads();
#pragma unroll
    for (int i = 0; i < 2; i++) {
        int idx = i * 256 + t;
        int c = idx >> 3, r8 = (idx & 7) << 3;
        bf16_t tmp[8];
#pragma unroll
        for (int j = 0; j < 8; j++) tmp[j] = T[(r8 + j) * 68 + c];
        *(uint4*)(dst + (size_t)(c0 + c) * 4096 + r0 + r8) = *(const uint4*)tmp;
    }
}

// ---------------------------------------------------------------------------
// C[2048, n_off + 128*gridDim.x cols] = A[2048,4096] @ Wt[*,4096]^T.
// 512 threads (8 waves, 2x4; 64x32 per wave), 128x128 tile, BK=32,
// double-buffered LDS: glld16 for B(Wt), register-prefetch for A (dtype-
// flexible), ONE barrier per K-step with loads issued right after it so the
// vmcnt drain at the NEXT barrier lands after a full compute phase.
// AHS: A is hidden_states (dtype sniffed). TV: write V^T per head.
// CMAY32: C store dtype sniffed (final GEMM into d_out).
// ---------------------------------------------------------------------------
template <bool AHS, bool TV, bool CMAY32>
__global__ __launch_bounds__(512, 4) void gemm_nt(
    const void* __restrict__ Ain, const bf16_t* __restrict__ Bt,
    void* __restrict__ Cout, int n_off, const void* __restrict__ hs) {
    constexpr int K = 4096, NITER = K / 32;
    const bool isbf = (AHS || CMAY32) ? detect_bf16(hs) : true;
    __shared__ bf16_t As[2][128 * 32];
    __shared__ bf16_t Bs[2][128 * 32];
    const int t = threadIdx.x;
    const int w = t >> 6, l = t & 63, l15 = l & 15, q = l >> 4;
    const int m0 = blockIdx.y * 128, n0 = blockIdx.x * 128;
    const int wm = (w >> 2) * 64, wn = (w & 3) * 32;
    floatx4 acc[4][2];
#pragma unroll
    for (int mi = 0; mi < 4; mi++)
#pragma unroll
        for (int ni = 0; ni < 2; ni++) acc[mi][ni] = floatx4{0.f, 0.f, 0.f, 0.f};

    const int ar = t >> 2, ac = (t & 3) << 3;       // staging: row 0..127, col {0,8,16,24}
    const bf16_t* Ab = (const bf16_t*)Ain;
    const float*  Af = (const float*)Ain;
    const bf16_t* gb = Bt + (size_t)(n0 + ar) * K + ac;
    const int lofs = ar * 32 + ac;                  // == 8*t (16B/lane, wave-linear)

    bf16_t areg[8];
    float  freg[8];

    auto loadA = [&](int ki) {
        if (AHS && !isbf) {
            const float* s = Af + (size_t)(m0 + ar) * K + ki * 32 + ac;
            *(float4*)&freg[0] = *(const float4*)s;
            *(float4*)&freg[4] = *(const float4*)(s + 4);
        } else {
            *(uint4*)areg = *(const uint4*)(Ab + (size_t)(m0 + ar) * K + ki * 32 + ac);
        }
    };
    auto writeA = [&](int p) {
        if (AHS && !isbf) {
            bf16_t tmp[8];
#pragma unroll
            for (int j = 0; j < 8; j++) tmp[j] = (bf16_t)freg[j];
            *(uint4*)&As[p][lofs] = *(const uint4*)tmp;
        } else {
            *(uint4*)&As[p][lofs] = *(const uint4*)areg;
        }
    };

    // Prologue: tile0 -> buf0; aregs <- tile1.
    loadA(0);
    writeA(0);
    glld16(gb, &Bs[0][lofs]);
    loadA(1);

    int p = 0;
    for (int i = 0; i < NITER; i++) {
        __syncthreads();   // buf[p] complete (compiler drains vmcnt+lgkm here)
        if (i + 1 < NITER) {
            glld16(gb + (i + 1) * 32, &Bs[p ^ 1][lofs]);   // in flight over compute
            writeA(p ^ 1);                                  // aregs = tile i+1 (landed)
            if (i + 2 < NITER) loadA(i + 2);                // regs <- tile i+2
        }
        bf16x8 af[4], bfr[2];
#pragma unroll
        for (int ii = 0; ii < 4; ii++)
            af[ii] = *(const bf16x8*)&As[p][(wm + ii * 16 + l15) * 32 + q * 8];
#pragma unroll
        for (int jj = 0; jj < 2; jj++)
            bfr[jj] = *(const bf16x8*)&Bs[p][(wn + jj * 16 + l15) * 32 + q * 8];
#pragma unroll
        for (int mi = 0; mi < 4; mi++)
#pragma unroll
            for (int ni = 0; ni < 2; ni++)
                acc[mi][ni] = MFMA16x16x32(af[mi], bfr[ni], acc[mi][ni]);
        p ^= 1;
    }

    if (TV) {
        bf16_t* C = (bf16_t*)Cout;
#pragma unroll
        for (int mi = 0; mi < 4; mi++) {
            int s_base = m0 + wm + mi * 16 + q * 4;
#pragma unroll
            for (int ni = 0; ni < 2; ni++) {
                int e = n_off + n0 + wn + ni * 16 + l15;
                int h = e >> 8, dd = e & 255;
                bf16_t o4[4];
#pragma unroll
                for (int r = 0; r < 4; r++) o4[r] = (bf16_t)acc[mi][ni][r];
                *(uint2*)(C + (size_t)h * 524288 + (size_t)dd * 2048 + s_base) =
                    *(const uint2*)o4;
            }
        }
    } else if (CMAY32 && !isbf) {
        float* C = (float*)Cout;
#pragma unroll
        for (int mi = 0; mi < 4; mi++)
#pragma unroll
            for (int ni = 0; ni < 2; ni++)
#pragma unroll
                for (int r = 0; r < 4; r++) {
                    int row = m0 + wm + mi * 16 + q * 4 + r;
                    int col = n_off + n0 + wn + ni * 16 + l15;
                    C[(size_t)row * 4096 + col] = acc[mi][ni][r];
                }
    } else {
        bf16_t* C = (bf16_t*)Cout;
#pragma unroll
        for (int mi = 0; mi < 4; mi++)
#pragma unroll
            for (int ni = 0; ni < 2; ni++)
#pragma unroll
                for (int r = 0; r < 4; r++) {
                    int row = m0 + wm + mi * 16 + q * 4 + r;
                    int col = n_off + n0 + wn + ni * 16 + l15;
                    C[(size_t)row * 4096 + col] = (bf16_t)acc[mi][ni][r];
                }
    }
}

// ---------------------------------------------------------------------------
// GPT-J interleaved RoPE on first 64 dims of each 256-dim head, Q and K (bf16).
// ---------------------------------------------------------------------------
__global__ __launch_bounds__(256) void rope_qk(
    bf16_t* __restrict__ Q, bf16_t* __restrict__ K,
    const int* __restrict__ pos_ids) {
    int tid = blockIdx.x * 256 + threadIdx.x;
    int i = tid & 31;
    int h = (tid >> 5) & 15;
    int s = tid >> 9;
    float p = (float)pos_ids[s];
    float inv = __expf(-(float)i * 0.28782313662425572f);  // 10000^(-i/32)
    float ang = p * inv;
    float sn, cs;
    __sincosf(ang, &sn, &cs);
    size_t base = (size_t)s * 4096 + h * 256 + 2 * i;
    float q0 = (float)Q[base], q1 = (float)Q[base + 1];
    Q[base]     = (bf16_t)(q0 * cs - q1 * sn);
    Q[base + 1] = (bf16_t)(q1 * cs + q0 * sn);
    float k0 = (float)K[base], k1 = (float)K[base + 1];
    K[base]     = (bf16_t)(k0 * cs - k1 * sn);
    K[base + 1] = (bf16_t)(k1 * cs + k0 * sn);
}

// ---------------------------------------------------------------------------
// Flash attention: block = (64 q-rows, head), 4 waves x 16 q-rows, 32-key
// tiles, online softmax, P via LDS. (unchanged from round 3 - verified)
// ---------------------------------------------------------------------------
__global__ __launch_bounds__(256) void attn_kernel(
    const bf16_t* __restrict__ Q, const bf16_t* __restrict__ K,
    const bf16_t* __restrict__ Vt, bf16_t* __restrict__ Ctx) {
    __shared__ bf16_t Ks[32 * 264];
    __shared__ bf16_t Vs[256 * 40];
    __shared__ bf16_t Ps[4 * 16 * 40];
    const int qt = blockIdx.x, h = blockIdx.y;
    const int t = threadIdx.x, w = t >> 6, l = t & 63, l15 = l & 15, q = l >> 4;
    const int qr = qt * 64 + w * 16;

    bf16x8 qf[8];
    {
        const bf16_t* qp = Q + (size_t)(qr + l15) * 4096 + h * 256 + q * 8;
#pragma unroll
        for (int tt = 0; tt < 8; tt++) qf[tt] = *(const bf16x8*)(qp + tt * 32);
    }
    floatx4 O[16];
#pragma unroll
    for (int i = 0; i < 16; i++) O[i] = floatx4{0.f, 0.f, 0.f, 0.f};
    float mrow[4] = {-1e30f, -1e30f, -1e30f, -1e30f};
    float lrow[4] = {0.f, 0.f, 0.f, 0.f};

    const int nkt = 2 * qt + 2;
    for (int kt = 0; kt < nkt; kt++) {
        __syncthreads();
#pragma unroll
        for (int i = 0; i < 4; i++) {
            int idx = i * 256 + t;
            int key = idx >> 5, d16 = (idx & 31) << 3;
            uint4 v = *(const uint4*)(K + (size_t)(kt * 32 + key) * 4096 + h * 256 + d16);
            *(uint4*)&Ks[key * 264 + d16] = v;
        }
#pragma unroll
        for (int i = 0; i < 4; i++) {
            int idx = i * 256 + t;
            int d = idx >> 2, k8 = (idx & 3) << 3;
            uint4 v = *(const uint4*)(Vt + (size_t)h * 524288 + (size_t)d * 2048 + kt * 32 + k8);
            *(uint4*)&Vs[d * 40 + k8] = v;
        }
        __syncthreads();

        floatx4 sc[2];
        sc[0] = floatx4{0.f, 0.f, 0.f, 0.f};
        sc[1] = floatx4{0.f, 0.f, 0.f, 0.f};
#pragma unroll
        for (int tt = 0; tt < 8; tt++) {
            bf16x8 k0f = *(const bf16x8*)&Ks[l15 * 264 + tt * 32 + q * 8];
            bf16x8 k1f = *(const bf16x8*)&Ks[(16 + l15) * 264 + tt * 32 + q * 8];
            sc[0] = MFMA16x16x32(qf[tt], k0f, sc[0]);
            sc[1] = MFMA16x16x32(qf[tt], k1f, sc[1]);
        }

        const bool diag = (kt >= 2 * qt);
#pragma unroll
        for (int r = 0; r < 4; r++) {
            int grow = qr + q * 4 + r;
            float v0 = sc[0][r] * 0.0625f;
            float v1 = sc[1][r] * 0.0625f;
            if (diag) {
                if (kt * 32 + l15 > grow) v0 = -1e30f;
                if (kt * 32 + 16 + l15 > grow) v1 = -1e30f;
            }
            float mx = fmaxf(v0, v1);
#pragma unroll
            for (int d = 1; d < 16; d <<= 1) mx = fmaxf(mx, __shfl_xor(mx, d, 64));
            float mnew = fmaxf(mrow[r], mx);
            float p0 = __expf(v0 - mnew), p1 = __expf(v1 - mnew);
            float rsum = p0 + p1;
#pragma unroll
            for (int d = 1; d < 16; d <<= 1) rsum += __shfl_xor(rsum, d, 64);
            float alpha = __expf(mrow[r] - mnew);
            lrow[r] = lrow[r] * alpha + rsum;
            mrow[r] = mnew;
#pragma unroll
            for (int ni = 0; ni < 16; ni++) O[ni][r] *= alpha;
            Ps[w * 640 + (q * 4 + r) * 40 + l15] = (bf16_t)p0;
            Ps[w * 640 + (q * 4 + r) * 40 + 16 + l15] = (bf16_t)p1;
        }
        __syncthreads();

        bf16x8 pf = *(const bf16x8*)&Ps[w * 640 + l15 * 40 + q * 8];
#pragma unroll
        for (int ni = 0; ni < 16; ni++) {
            bf16x8 vf = *(const bf16x8*)&Vs[(ni * 16 + l15) * 40 + q * 8];
            O[ni] = MFMA16x16x32(pf, vf, O[ni]);
        }
    }
#pragma unroll
    for (int ni = 0; ni < 16; ni++)
#pragma unroll
        for (int r = 0; r < 4; r++) {
            int grow = qr + q * 4 + r;
            Ctx[(size_t)grow * 4096 + h * 256 + ni * 16 + l15] =
                (bf16_t)(O[ni][r] / lrow[r]);
        }
}

// ---------------------------------------------------------------------------
// Workspace (48 MB): R0=[0,16M) R1=[16,32M) R2=[32,48M).
//   Q: Wt(wq) full 32MB in R0+R1, grid 512 -> Q in d_out.
//   K: Wt(wk) full 32MB in R0+R1 -> K in R2.
//   V: striped; Wt stripe in R0 (R1 freed) -> Vt in R1.
//   attn: Ctx -> R0.   O: Wt(wo) stripes in R2 (K dead) -> d_out (Q dead).
// ---------------------------------------------------------------------------
extern "C" void kernel_launch(void* const* d_in, const int* in_sizes, int n_in,
                              void* d_out, int out_size, void* d_ws, size_t ws_size,
                              hipStream_t stream) {
    const void* hs = d_in[0];
    const void* wq = d_in[1];
    const void* wk = d_in[2];
    const void* wv = d_in[3];
    const void* wo = d_in[4];
    const int* pos = (const int*)d_in[5];

    char* ws = (char*)d_ws;
    bf16_t* R0 = (bf16_t*)ws;
    bf16_t* R1 = (bf16_t*)(ws + ((size_t)16 << 20));
    bf16_t* R2 = (bf16_t*)(ws + ((size_t)32 << 20));
    bf16_t* Qb  = (bf16_t*)d_out;
    bf16_t* Kb  = R2;
    bf16_t* Vt  = R1;
    bf16_t* Ctx = R0;

    dim3 tT(256), tG(512), tb(256);
    dim3 gTfull(64, 64), gThalf(64, 32);
    dim3 gGfull(32, 16), gGhalf(16, 16);

    // Q = hs @ wq  (full width; Wt = R0+R1)
    transpose_w<<<gTfull, tT, 0, stream>>>(wq, R0, 0, hs);
    gemm_nt<true, false, false><<<gGfull, tG, 0, stream>>>(hs, R0, Qb, 0, hs);
    // K = hs @ wk
    transpose_w<<<gTfull, tT, 0, stream>>>(wk, R0, 0, hs);
    gemm_nt<true, false, false><<<gGfull, tG, 0, stream>>>(hs, R0, Kb, 0, hs);
    // Vt = (hs @ wv)^T per head (striped; Wt stripe in R0, Vt in R1)
    transpose_w<<<gThalf, tT, 0, stream>>>(wv, R0, 0, hs);
    gemm_nt<true, true, false><<<gGhalf, tG, 0, stream>>>(hs, R0, Vt, 0, hs);
    transpose_w<<<gThalf, tT, 0, stream>>>(wv, R0, 2048, hs);
    gemm_nt<true, true, false><<<gGhalf, tG, 0, stream>>>(hs, R0, Vt, 2048, hs);

    rope_qk<<<dim3(4096), tb, 0, stream>>>(Qb, Kb, pos);

    attn_kernel<<<dim3(32, 16), tb, 0, stream>>>(Qb, Kb, Vt, Ctx);

    // out = Ctx @ wo  (striped; Wt in R2, K dead; d_out reused, Q dead)
    transpose_w<<<gThalf, tT, 0, stream>>>(wo, R2, 0, hs);
    gemm_nt<false, false, true><<<gGhalf, tG, 0, stream>>>(Ctx, R2, d_out, 0, hs);
    transpose_w<<<gThalf, tT, 0, stream>>>(wo, R2, 2048, hs);
    gemm_nt<false, false, true><<<gGhalf, tG, 0, stream>>>(Ctx, R2, d_out, 2048, hs);
}

// Round 5
// 779.889 us; speedup vs baseline: 2.3950x; 1.5133x over previous
//
#include <hip/hip_runtime.h>
#include <hip/hip_bf16.h>

typedef __bf16 bf16_t;
typedef __attribute__((ext_vector_type(8))) __bf16 bf16x8;
typedef __attribute__((ext_vector_type(4))) float floatx4;

#define MFMA16x16x32(a, b, c) __builtin_amdgcn_mfma_f32_16x16x32_bf16((a), (b), (c), 0, 0, 0)

__device__ __forceinline__ void glld16(const bf16_t* g, bf16_t* l) {
    __builtin_amdgcn_global_load_lds(
        (const __attribute__((address_space(1))) unsigned int*)g,
        (__attribute__((address_space(3))) unsigned int*)l,
        16, 0, 0);
}

// ---------------------------------------------------------------------------
// On-device dtype sniffer (proven round 3): bf16-pair u32 bits 14..7 are the
// low element's exponent, in [112,142] for N(0,1)-ish data; fp32 -> uniform.
// ---------------------------------------------------------------------------
__device__ __forceinline__ bool detect_bf16(const void* hs) {
    const unsigned* u = (const unsigned*)hs;
    int c = 0;
#pragma unroll 8
    for (int i = 0; i < 64; i++) {
        unsigned e = (u[i] >> 7) & 0xFFu;
        c += (e >= 112u && e <= 142u) ? 1 : 0;
    }
    return c >= 32;
}

// ---------------------------------------------------------------------------
// hs -> bf16 copy/convert (fast path). 8 elems/thread.
// ---------------------------------------------------------------------------
__global__ __launch_bounds__(256) void conv_hs(
    const void* __restrict__ src, bf16_t* __restrict__ dst) {
    const bool isbf = detect_bf16(src);
    size_t i8 = ((size_t)blockIdx.x * 256 + threadIdx.x) * 8;
    if (isbf) {
        *(uint4*)(dst + i8) = *(const uint4*)((const bf16_t*)src + i8);
    } else {
        const float* s = (const float*)src + i8;
        float4 f0 = *(const float4*)s;
        float4 f1 = *(const float4*)(s + 4);
        bf16_t tmp[8];
        tmp[0] = (bf16_t)f0.x; tmp[1] = (bf16_t)f0.y;
        tmp[2] = (bf16_t)f0.z; tmp[3] = (bf16_t)f0.w;
        tmp[4] = (bf16_t)f1.x; tmp[5] = (bf16_t)f1.y;
        tmp[6] = (bf16_t)f1.z; tmp[7] = (bf16_t)f1.w;
        *(uint4*)(dst + i8) = *(const uint4*)tmp;
    }
}

// ---------------------------------------------------------------------------
// 64x64-tiled transpose of W cols [coff, coff+64*gridDim.y) into bf16
// Wt[c][r] (dst row-stride 4096). Source dtype sniffed from hs.
// ---------------------------------------------------------------------------
__global__ __launch_bounds__(256) void transpose_w(
    const void* __restrict__ src, bf16_t* __restrict__ dst,
    int coff, const void* __restrict__ hs) {
    const bool isbf = detect_bf16(hs);
    __shared__ bf16_t T[64 * 68];
    const int r0 = blockIdx.x * 64, c0 = blockIdx.y * 64;
    const int t = threadIdx.x;
#pragma unroll
    for (int i = 0; i < 2; i++) {
        int idx = i * 256 + t;
        int r = idx >> 3, c8 = (idx & 7) << 3;
        bf16_t tmp[8];
        if (isbf) {
            *(uint4*)tmp = *(const uint4*)((const bf16_t*)src +
                              (size_t)(r0 + r) * 4096 + coff + c0 + c8);
        } else {
            const float* s = (const float*)src + (size_t)(r0 + r) * 4096 + coff + c0 + c8;
            float4 f0 = *(const float4*)s;
            float4 f1 = *(const float4*)(s + 4);
            tmp[0] = (bf16_t)f0.x; tmp[1] = (bf16_t)f0.y;
            tmp[2] = (bf16_t)f0.z; tmp[3] = (bf16_t)f0.w;
            tmp[4] = (bf16_t)f1.x; tmp[5] = (bf16_t)f1.y;
            tmp[6] = (bf16_t)f1.z; tmp[7] = (bf16_t)f1.w;
        }
        *(uint2*)&T[r * 68 + c8]     = *(const uint2*)&tmp[0];
        *(uint2*)&T[r * 68 + c8 + 4] = *(const uint2*)&tmp[4];
    }
    __syncthreads();
#pragma unroll
    for (int i = 0; i < 2; i++) {
        int idx = i * 256 + t;
        int c = idx >> 3, r8 = (idx & 7) << 3;
        bf16_t tmp[8];
#pragma unroll
        for (int j = 0; j < 8; j++) tmp[j] = T[(r8 + j) * 68 + c];
        *(uint4*)(dst + (size_t)(c0 + c) * 4096 + r0 + r8) = *(const uint4*)tmp;
    }
}

// ---------------------------------------------------------------------------
// FAST-PATH GEMM (m97 structure, bf16 A): C[2048,4096] = A @ Bt^T.
// 256 threads = 4 waves (2x2 of 64x64), 128x128 tile, BK=32, glld16 x4.
// TV: write V^T per head. C32: store dtype sniffed (fp32 out for final GEMM).
// ---------------------------------------------------------------------------
template <bool TV, bool C32>
__global__ __launch_bounds__(256, 2) void gemm_bf16a(
    const bf16_t* __restrict__ A, const bf16_t* __restrict__ Bt,
    void* __restrict__ Cout, const void* __restrict__ hs) {
    constexpr int K = 4096;
    __shared__ bf16_t As[128 * 32];
    __shared__ bf16_t Bs[128 * 32];
    const bool isbf = C32 ? detect_bf16(hs) : true;
    const int t = threadIdx.x;
    const int w = t >> 6, l = t & 63, l15 = l & 15, q = l >> 4;
    const int m0 = blockIdx.y * 128, n0 = blockIdx.x * 128;
    const int wm = (w >> 1) * 64, wn = (w & 1) * 64;
    floatx4 acc[4][4];
#pragma unroll
    for (int mi = 0; mi < 4; mi++)
#pragma unroll
        for (int ni = 0; ni < 4; ni++) acc[mi][ni] = floatx4{0.f, 0.f, 0.f, 0.f};

    const bf16_t* ga = A + (size_t)(m0 + (t >> 2)) * K + ((t & 3) << 3);
    const bf16_t* gb = Bt + (size_t)(n0 + (t >> 2)) * K + ((t & 3) << 3);
    bf16_t* lA = &As[(t >> 2) * 32 + ((t & 3) << 3)];
    bf16_t* lB = &Bs[(t >> 2) * 32 + ((t & 3) << 3)];

    for (int k0 = 0; k0 < K; k0 += 32) {
        __syncthreads();
        glld16(ga, lA);
        glld16(ga + (size_t)64 * K, lA + 64 * 32);
        glld16(gb, lB);
        glld16(gb + (size_t)64 * K, lB + 64 * 32);
        ga += 32; gb += 32;
        __syncthreads();
        bf16x8 af[4], bfr[4];
#pragma unroll
        for (int i = 0; i < 4; i++)
            af[i] = *(const bf16x8*)&As[(wm + i * 16 + l15) * 32 + q * 8];
#pragma unroll
        for (int i = 0; i < 4; i++)
            bfr[i] = *(const bf16x8*)&Bs[(wn + i * 16 + l15) * 32 + q * 8];
#pragma unroll
        for (int mi = 0; mi < 4; mi++)
#pragma unroll
            for (int ni = 0; ni < 4; ni++)
                acc[mi][ni] = MFMA16x16x32(af[mi], bfr[ni], acc[mi][ni]);
    }

    if (TV) {
        bf16_t* C = (bf16_t*)Cout;
#pragma unroll
        for (int mi = 0; mi < 4; mi++) {
            int s_base = m0 + wm + mi * 16 + q * 4;
#pragma unroll
            for (int ni = 0; ni < 4; ni++) {
                int e = n0 + wn + ni * 16 + l15;
                int h = e >> 8, dd = e & 255;
                bf16_t o4[4];
#pragma unroll
                for (int r = 0; r < 4; r++) o4[r] = (bf16_t)acc[mi][ni][r];
                *(uint2*)(C + (size_t)h * 524288 + (size_t)dd * 2048 + s_base) =
                    *(const uint2*)o4;
            }
        }
    } else if (C32 && !isbf) {
        float* C = (float*)Cout;
#pragma unroll
        for (int mi = 0; mi < 4; mi++)
#pragma unroll
            for (int ni = 0; ni < 4; ni++)
#pragma unroll
                for (int r = 0; r < 4; r++) {
                    int row = m0 + wm + mi * 16 + q * 4 + r;
                    int col = n0 + wn + ni * 16 + l15;
                    C[(size_t)row * 4096 + col] = acc[mi][ni][r];
                }
    } else {
        bf16_t* C = (bf16_t*)Cout;
#pragma unroll
        for (int mi = 0; mi < 4; mi++)
#pragma unroll
            for (int ni = 0; ni < 4; ni++)
#pragma unroll
                for (int r = 0; r < 4; r++) {
                    int row = m0 + wm + mi * 16 + q * 4 + r;
                    int col = n0 + wn + ni * 16 + l15;
                    C[(size_t)row * 4096 + col] = (bf16_t)acc[mi][ni][r];
                }
    }
}

// ---------------------------------------------------------------------------
// FALLBACK GEMM (round-4, proven): 512 threads, dbuf, register-A (fp32-able).
// ---------------------------------------------------------------------------
template <bool AHS, bool TV, bool CMAY32>
__global__ __launch_bounds__(512, 4) void gemm_nt(
    const void* __restrict__ Ain, const bf16_t* __restrict__ Bt,
    void* __restrict__ Cout, int n_off, const void* __restrict__ hs) {
    constexpr int K = 4096, NITER = K / 32;
    const bool isbf = (AHS || CMAY32) ? detect_bf16(hs) : true;
    __shared__ bf16_t As[2][128 * 32];
    __shared__ bf16_t Bs[2][128 * 32];
    const int t = threadIdx.x;
    const int w = t >> 6, l = t & 63, l15 = l & 15, q = l >> 4;
    const int m0 = blockIdx.y * 128, n0 = blockIdx.x * 128;
    const int wm = (w >> 2) * 64, wn = (w & 3) * 32;
    floatx4 acc[4][2];
#pragma unroll
    for (int mi = 0; mi < 4; mi++)
#pragma unroll
        for (int ni = 0; ni < 2; ni++) acc[mi][ni] = floatx4{0.f, 0.f, 0.f, 0.f};

    const int ar = t >> 2, ac = (t & 3) << 3;
    const bf16_t* Ab = (const bf16_t*)Ain;
    const float*  Af = (const float*)Ain;
    const bf16_t* gb = Bt + (size_t)(n0 + ar) * K + ac;
    const int lofs = ar * 32 + ac;

    bf16_t areg[8];
    float  freg[8];

    auto loadA = [&](int ki) {
        if (AHS && !isbf) {
            const float* s = Af + (size_t)(m0 + ar) * K + ki * 32 + ac;
            *(float4*)&freg[0] = *(const float4*)s;
            *(float4*)&freg[4] = *(const float4*)(s + 4);
        } else {
            *(uint4*)areg = *(const uint4*)(Ab + (size_t)(m0 + ar) * K + ki * 32 + ac);
        }
    };
    auto writeA = [&](int p) {
        if (AHS && !isbf) {
            bf16_t tmp[8];
#pragma unroll
            for (int j = 0; j < 8; j++) tmp[j] = (bf16_t)freg[j];
            *(uint4*)&As[p][lofs] = *(const uint4*)tmp;
        } else {
            *(uint4*)&As[p][lofs] = *(const uint4*)areg;
        }
    };

    loadA(0);
    writeA(0);
    glld16(gb, &Bs[0][lofs]);
    loadA(1);

    int p = 0;
    for (int i = 0; i < NITER; i++) {
        __syncthreads();
        if (i + 1 < NITER) {
            glld16(gb + (i + 1) * 32, &Bs[p ^ 1][lofs]);
            writeA(p ^ 1);
            if (i + 2 < NITER) loadA(i + 2);
        }
        bf16x8 af[4], bfr[2];
#pragma unroll
        for (int ii = 0; ii < 4; ii++)
            af[ii] = *(const bf16x8*)&As[p][(wm + ii * 16 + l15) * 32 + q * 8];
#pragma unroll
        for (int jj = 0; jj < 2; jj++)
            bfr[jj] = *(const bf16x8*)&Bs[p][(wn + jj * 16 + l15) * 32 + q * 8];
#pragma unroll
        for (int mi = 0; mi < 4; mi++)
#pragma unroll
            for (int ni = 0; ni < 2; ni++)
                acc[mi][ni] = MFMA16x16x32(af[mi], bfr[ni], acc[mi][ni]);
        p ^= 1;
    }

    if (TV) {
        bf16_t* C = (bf16_t*)Cout;
#pragma unroll
        for (int mi = 0; mi < 4; mi++) {
            int s_base = m0 + wm + mi * 16 + q * 4;
#pragma unroll
            for (int ni = 0; ni < 2; ni++) {
                int e = n_off + n0 + wn + ni * 16 + l15;
                int h = e >> 8, dd = e & 255;
                bf16_t o4[4];
#pragma unroll
                for (int r = 0; r < 4; r++) o4[r] = (bf16_t)acc[mi][ni][r];
                *(uint2*)(C + (size_t)h * 524288 + (size_t)dd * 2048 + s_base) =
                    *(const uint2*)o4;
            }
        }
    } else if (CMAY32 && !isbf) {
        float* C = (float*)Cout;
#pragma unroll
        for (int mi = 0; mi < 4; mi++)
#pragma unroll
            for (int ni = 0; ni < 2; ni++)
#pragma unroll
                for (int r = 0; r < 4; r++) {
                    int row = m0 + wm + mi * 16 + q * 4 + r;
                    int col = n_off + n0 + wn + ni * 16 + l15;
                    C[(size_t)row * 4096 + col] = acc[mi][ni][r];
                }
    } else {
        bf16_t* C = (bf16_t*)Cout;
#pragma unroll
        for (int mi = 0; mi < 4; mi++)
#pragma unroll
            for (int ni = 0; ni < 2; ni++)
#pragma unroll
                for (int r = 0; r < 4; r++) {
                    int row = m0 + wm + mi * 16 + q * 4 + r;
                    int col = n_off + n0 + wn + ni * 16 + l15;
                    C[(size_t)row * 4096 + col] = (bf16_t)acc[mi][ni][r];
                }
    }
}

// ---------------------------------------------------------------------------
// GPT-J interleaved RoPE on first 64 dims of each 256-dim head, Q and K.
// ---------------------------------------------------------------------------
__global__ __launch_bounds__(256) void rope_qk(
    bf16_t* __restrict__ Q, bf16_t* __restrict__ K,
    const int* __restrict__ pos_ids) {
    int tid = blockIdx.x * 256 + threadIdx.x;
    int i = tid & 31;
    int h = (tid >> 5) & 15;
    int s = tid >> 9;
    float p = (float)pos_ids[s];
    float inv = __expf(-(float)i * 0.28782313662425572f);  // 10000^(-i/32)
    float ang = p * inv;
    float sn, cs;
    __sincosf(ang, &sn, &cs);
    size_t base = (size_t)s * 4096 + h * 256 + 2 * i;
    float q0 = (float)Q[base], q1 = (float)Q[base + 1];
    Q[base]     = (bf16_t)(q0 * cs - q1 * sn);
    Q[base + 1] = (bf16_t)(q1 * cs + q0 * sn);
    float k0 = (float)K[base], k1 = (float)K[base + 1];
    K[base]     = (bf16_t)(k0 * cs - k1 * sn);
    K[base + 1] = (bf16_t)(k1 * cs + k0 * sn);
}

// ---------------------------------------------------------------------------
// Flash attention, CAUSAL-BALANCED: block bx handles q-tiles {bx, 31-bx}
// sequentially -> every block does exactly 66 k-tiles (no tail). Grid (16,16).
// ---------------------------------------------------------------------------
__global__ __launch_bounds__(256) void attn_kernel(
    const bf16_t* __restrict__ Q, const bf16_t* __restrict__ K,
    const bf16_t* __restrict__ Vt, bf16_t* __restrict__ Ctx) {
    __shared__ bf16_t Ks[32 * 264];
    __shared__ bf16_t Vs[256 * 40];
    __shared__ bf16_t Ps[4 * 16 * 40];
    const int h = blockIdx.y;
    const int t = threadIdx.x, w = t >> 6, l = t & 63, l15 = l & 15, q = l >> 4;

    for (int pass = 0; pass < 2; pass++) {
        const int qt = pass ? (31 - (int)blockIdx.x) : (int)blockIdx.x;
        const int qr = qt * 64 + w * 16;

        bf16x8 qf[8];
        {
            const bf16_t* qp = Q + (size_t)(qr + l15) * 4096 + h * 256 + q * 8;
#pragma unroll
            for (int tt = 0; tt < 8; tt++) qf[tt] = *(const bf16x8*)(qp + tt * 32);
        }
        floatx4 O[16];
#pragma unroll
        for (int i = 0; i < 16; i++) O[i] = floatx4{0.f, 0.f, 0.f, 0.f};
        float mrow[4] = {-1e30f, -1e30f, -1e30f, -1e30f};
        float lrow[4] = {0.f, 0.f, 0.f, 0.f};

        const int nkt = 2 * qt + 2;
        for (int kt = 0; kt < nkt; kt++) {
            __syncthreads();
#pragma unroll
            for (int i = 0; i < 4; i++) {
                int idx = i * 256 + t;
                int key = idx >> 5, d16 = (idx & 31) << 3;
                uint4 v = *(const uint4*)(K + (size_t)(kt * 32 + key) * 4096 + h * 256 + d16);
                *(uint4*)&Ks[key * 264 + d16] = v;
            }
#pragma unroll
            for (int i = 0; i < 4; i++) {
                int idx = i * 256 + t;
                int d = idx >> 2, k8 = (idx & 3) << 3;
                uint4 v = *(const uint4*)(Vt + (size_t)h * 524288 + (size_t)d * 2048 + kt * 32 + k8);
                *(uint4*)&Vs[d * 40 + k8] = v;
            }
            __syncthreads();

            floatx4 sc[2];
            sc[0] = floatx4{0.f, 0.f, 0.f, 0.f};
            sc[1] = floatx4{0.f, 0.f, 0.f, 0.f};
#pragma unroll
            for (int tt = 0; tt < 8; tt++) {
                bf16x8 k0f = *(const bf16x8*)&Ks[l15 * 264 + tt * 32 + q * 8];
                bf16x8 k1f = *(const bf16x8*)&Ks[(16 + l15) * 264 + tt * 32 + q * 8];
                sc[0] = MFMA16x16x32(qf[tt], k0f, sc[0]);
                sc[1] = MFMA16x16x32(qf[tt], k1f, sc[1]);
            }

            const bool diag = (kt >= 2 * qt);
#pragma unroll
            for (int r = 0; r < 4; r++) {
                int grow = qr + q * 4 + r;
                float v0 = sc[0][r] * 0.0625f;
                float v1 = sc[1][r] * 0.0625f;
                if (diag) {
                    if (kt * 32 + l15 > grow) v0 = -1e30f;
                    if (kt * 32 + 16 + l15 > grow) v1 = -1e30f;
                }
                float mx = fmaxf(v0, v1);
#pragma unroll
                for (int d = 1; d < 16; d <<= 1) mx = fmaxf(mx, __shfl_xor(mx, d, 64));
                float mnew = fmaxf(mrow[r], mx);
                float p0 = __expf(v0 - mnew), p1 = __expf(v1 - mnew);
                float rsum = p0 + p1;
#pragma unroll
                for (int d = 1; d < 16; d <<= 1) rsum += __shfl_xor(rsum, d, 64);
                float alpha = __expf(mrow[r] - mnew);
                lrow[r] = lrow[r] * alpha + rsum;
                mrow[r] = mnew;
#pragma unroll
                for (int ni = 0; ni < 16; ni++) O[ni][r] *= alpha;
                Ps[w * 640 + (q * 4 + r) * 40 + l15] = (bf16_t)p0;
                Ps[w * 640 + (q * 4 + r) * 40 + 16 + l15] = (bf16_t)p1;
            }
            __syncthreads();

            bf16x8 pf = *(const bf16x8*)&Ps[w * 640 + l15 * 40 + q * 8];
#pragma unroll
            for (int ni = 0; ni < 16; ni++) {
                bf16x8 vf = *(const bf16x8*)&Vs[(ni * 16 + l15) * 40 + q * 8];
                O[ni] = MFMA16x16x32(pf, vf, O[ni]);
            }
        }
#pragma unroll
        for (int ni = 0; ni < 16; ni++)
#pragma unroll
            for (int r = 0; r < 4; r++) {
                int grow = qr + q * 4 + r;
                Ctx[(size_t)grow * 4096 + h * 256 + ni * 16 + l15] =
                    (bf16_t)(O[ni][r] / lrow[r]);
            }
    }
}

// ---------------------------------------------------------------------------
// FAST path (ws >= 80MB):  A0=[0,16M) Hb->Ctx | A1=[16,48M) Wt | A2=[48,64M) K
//                          | A3=[64,80M) Vt | Q in d_out.
// FALLBACK (48MB, round-4 proven): R0 Wt/Ctx | R1 Vt | R2 K | Q in d_out.
// Branch on ws_size: constant every call -> graph-safe.
// ---------------------------------------------------------------------------
extern "C" void kernel_launch(void* const* d_in, const int* in_sizes, int n_in,
                              void* d_out, int out_size, void* d_ws, size_t ws_size,
                              hipStream_t stream) {
    const void* hs = d_in[0];
    const void* wq = d_in[1];
    const void* wk = d_in[2];
    const void* wv = d_in[3];
    const void* wo = d_in[4];
    const int* pos = (const int*)d_in[5];

    char* ws = (char*)d_ws;
    dim3 tT(256), tb(256);
    dim3 gTfull(64, 64);
    bf16_t* Qb = (bf16_t*)d_out;

    if (ws_size >= ((size_t)80 << 20)) {
        // ---------------- fast path: m97 GEMMs on bf16 hs ----------------
        bf16_t* Hb  = (bf16_t*)ws;                          // -> Ctx later
        bf16_t* Wt  = (bf16_t*)(ws + ((size_t)16 << 20));
        bf16_t* Kb  = (bf16_t*)(ws + ((size_t)48 << 20));
        bf16_t* Vt  = (bf16_t*)(ws + ((size_t)64 << 20));
        bf16_t* Ctx = Hb;
        dim3 gG(32, 16);

        conv_hs<<<dim3(4096), tb, 0, stream>>>(hs, Hb);

        transpose_w<<<gTfull, tT, 0, stream>>>(wq, Wt, 0, hs);
        gemm_bf16a<false, false><<<gG, tb, 0, stream>>>(Hb, Wt, Qb, hs);
        transpose_w<<<gTfull, tT, 0, stream>>>(wk, Wt, 0, hs);
        gemm_bf16a<false, false><<<gG, tb, 0, stream>>>(Hb, Wt, Kb, hs);
        transpose_w<<<gTfull, tT, 0, stream>>>(wv, Wt, 0, hs);
        gemm_bf16a<true, false><<<gG, tb, 0, stream>>>(Hb, Wt, Vt, hs);

        rope_qk<<<dim3(4096), tb, 0, stream>>>(Qb, Kb, pos);

        attn_kernel<<<dim3(16, 16), tb, 0, stream>>>(Qb, Kb, Vt, Ctx);  // Hb dead

        transpose_w<<<gTfull, tT, 0, stream>>>(wo, Wt, 0, hs);
        gemm_bf16a<false, true><<<gG, tb, 0, stream>>>(Ctx, Wt, d_out, hs);  // Q dead
    } else {
        // ---------------- fallback: round-4 proven 48 MB pipeline --------
        bf16_t* R0 = (bf16_t*)ws;
        bf16_t* R1 = (bf16_t*)(ws + ((size_t)16 << 20));
        bf16_t* R2 = (bf16_t*)(ws + ((size_t)32 << 20));
        bf16_t* Kb  = R2;
        bf16_t* Vt  = R1;
        bf16_t* Ctx = R0;
        dim3 tG(512);
        dim3 gThalf(64, 32);
        dim3 gGfull(32, 16), gGhalf(16, 16);

        transpose_w<<<gTfull, tT, 0, stream>>>(wq, R0, 0, hs);
        gemm_nt<true, false, false><<<gGfull, tG, 0, stream>>>(hs, R0, Qb, 0, hs);
        transpose_w<<<gTfull, tT, 0, stream>>>(wk, R0, 0, hs);
        gemm_nt<true, false, false><<<gGfull, tG, 0, stream>>>(hs, R0, Kb, 0, hs);
        transpose_w<<<gThalf, tT, 0, stream>>>(wv, R0, 0, hs);
        gemm_nt<true, true, false><<<gGhalf, tG, 0, stream>>>(hs, R0, Vt, 0, hs);
        transpose_w<<<gThalf, tT, 0, stream>>>(wv, R0, 2048, hs);
        gemm_nt<true, true, false><<<gGhalf, tG, 0, stream>>>(hs, R0, Vt, 2048, hs);

        rope_qk<<<dim3(4096), tb, 0, stream>>>(Qb, Kb, pos);

        attn_kernel<<<dim3(16, 16), tb, 0, stream>>>(Qb, Kb, Vt, Ctx);

        transpose_w<<<gThalf, tT, 0, stream>>>(wo, R2, 0, hs);
        gemm_nt<false, false, true><<<gGhalf, tG, 0, stream>>>(Ctx, R2, d_out, 0, hs);
        transpose_w<<<gThalf, tT, 0, stream>>>(wo, R2, 2048, hs);
        gemm_nt<false, false, true><<<gGhalf, tG, 0, stream>>>(Ctx, R2, d_out, 2048, hs);
    }
}